// Round 5
// baseline (230.437 us; speedup 1.0000x reference)
//
#include <hip/hip_runtime.h>
#include <hip/hip_bf16.h>
#include <math.h>

typedef short bf16x8 __attribute__((ext_vector_type(8)));
typedef float f32x4 __attribute__((ext_vector_type(4)));

constexpr int CIN = 32, COUT = 64, D = 16, H = 32, W = 32;

// ---------------- ws layout ----------------
// [0, 884736) : wtp bf16 [cls8][t27][co64][ci32]
constexpr size_t WS_NEED = 884736u;

// Per-wave item lists (full-co): item = (cls, alpha), code = cls + alpha*8.
static __device__ const unsigned char IT_CODE[24] = {
    0, 8, 16, 3,                  // w0 (93 taps, padded 102)
    1, 9, 17, 11, 19, 7,          // w1 (86, padded 90)
    2, 10, 18, 5, 13, 21, 15,     // w2 (98, padded 102)
    4, 12, 20, 6, 14, 22, 23};    // w3 (98, padded 102)
static __device__ const unsigned char IT_START[5] = {0, 4, 10, 17, 24};
static __device__ const unsigned char EPI_START[10] = {0, 1, 3, 5, 6, 7, 9, 11, 12, 13};
static __device__ const unsigned char EPI_CNT[10]   = {1, 2, 2, 1, 1, 2, 2, 1, 1, 2};

__global__ void prep_w(const float* __restrict__ w, unsigned short* __restrict__ wtp) {
    int idx = blockIdx.x * 256 + threadIdx.x;            // 442368 total
    int ci  = idx & 31;
    int co  = (idx >> 5) & 63;
    int tt  = idx >> 11;                                  // cls*27 + t
    int t   = tt % 27, cls = tt / 27;
    int td = t / 9, th = (t / 3) % 3, tw = t % 3;
    int pd = (cls >> 2) & 1, ph = (cls >> 1) & 1, pw = cls & 1;
    int kd = pd + 2 * td, kh = ph + 2 * th, kw = pw + 2 * tw;
    float v = 0.f;
    if (kd < 5 && kh < 5 && kw < 5)
        v = w[(ci * COUT + co) * 125 + kd * 25 + kh * 5 + kw];
    __hip_bfloat16 b = __float2bfloat16(v);
    wtp[idx] = *reinterpret_cast<unsigned short*>(&b);
}

__device__ __forceinline__ int lpA(int wrow, int quad) {
    return wrow * 64 + ((quad ^ ((wrow >> 1) & 3)) << 4);
}

// one N-column of a tap burst: 6 MFMA (3 beta-planes x 2 M-halves)
#define MFMA_N(nt, aa, bp)                                                                   \
    acc[0][0][nt] = __builtin_amdgcn_mfma_f32_16x16x32_bf16(a##aa##0, bp##nt, acc[0][0][nt], 0, 0, 0); \
    acc[0][1][nt] = __builtin_amdgcn_mfma_f32_16x16x32_bf16(a##aa##1, bp##nt, acc[0][1][nt], 0, 0, 0); \
    acc[1][0][nt] = __builtin_amdgcn_mfma_f32_16x16x32_bf16(a##aa##2, bp##nt, acc[1][0][nt], 0, 0, 0); \
    acc[1][1][nt] = __builtin_amdgcn_mfma_f32_16x16x32_bf16(a##aa##3, bp##nt, acc[1][1][nt], 0, 0, 0); \
    acc[2][0][nt] = __builtin_amdgcn_mfma_f32_16x16x32_bf16(a##aa##4, bp##nt, acc[2][0][nt], 0, 0, 0); \
    acc[2][1][nt] = __builtin_amdgcn_mfma_f32_16x16x32_bf16(a##aa##5, bp##nt, acc[2][1][nt], 0, 0, 0);

#define BURST(aa, bp)                                                        \
    __builtin_amdgcn_s_setprio(1);                                           \
    MFMA_N(0, aa, bp) MFMA_N(1, aa, bp) MFMA_N(2, aa, bp) MFMA_N(3, aa, bp)  \
    __builtin_amdgcn_s_setprio(0);

// A loads (LDS, depth-2 E/O). Walker invariant: at entry, A-walker = min(jA, T-1).
#define LOADA(aa)                                                                    \
    {                                                                                \
        int Qb = __builtin_amdgcn_readfirstlane(((alpha + 2 - aptd) * 5 + (2 - apth)) * 2048); \
        int ss = __builtin_amdgcn_readfirstlane(2 - aptw);                           \
        int lpa = ss == 0 ? lp00 : (ss == 1 ? lp01 : lp02);                          \
        int lpb = ss == 0 ? lp10 : (ss == 1 ? lp11 : lp12);                          \
        const char* rb = xsb + Qb;                                                   \
        a##aa##0 = *(const bf16x8*)(rb + lpa);                                       \
        a##aa##1 = *(const bf16x8*)(rb + lpb);                                       \
        a##aa##2 = *(const bf16x8*)(rb + 2048 + lpa);                                \
        a##aa##3 = *(const bf16x8*)(rb + 2048 + lpb);                                \
        a##aa##4 = *(const bf16x8*)(rb + 4096 + lpa);                                \
        a##aa##5 = *(const bf16x8*)(rb + 4096 + lpb);                                \
        ++jA;                                                                        \
        if (jA < T) { ++aptw; if (aptw == ntw) { aptw = 0; ++apth; if (apth == nth) { apth = 0; ++aptd; } } } \
    }

// B loads (global, depth-3 rotation). Taps >= T get a zero tile (MFMA no-op),
// so consumption can be padded to a multiple of 6 without corrupting acc.
#define LOADB(bp)                                                                    \
    {                                                                                \
        if (jB < T) {                                                                \
            int Boff = __builtin_amdgcn_readfirstlane((bptd * 9 + bpth * 3 + bptw) * 4096); \
            const char* bq = tbb + Boff;                                             \
            bp##0 = *(const bf16x8*)(bq);                                            \
            bp##1 = *(const bf16x8*)(bq + 1024);                                     \
            bp##2 = *(const bf16x8*)(bq + 2048);                                     \
            bp##3 = *(const bf16x8*)(bq + 3072);                                     \
        } else {                                                                     \
            bp##0 = (bf16x8){0, 0, 0, 0, 0, 0, 0, 0};                                \
            bp##1 = (bf16x8){0, 0, 0, 0, 0, 0, 0, 0};                                \
            bp##2 = (bf16x8){0, 0, 0, 0, 0, 0, 0, 0};                                \
            bp##3 = (bf16x8){0, 0, 0, 0, 0, 0, 0, 0};                                \
        }                                                                            \
        ++jB;                                                                        \
        if (jB < T) { ++bptw; if (bptw == ntw) { bptw = 0; ++bpth; if (bpth == nth) { bpth = 0; ++bptd; } } } \
    }

__global__ __launch_bounds__(256, 2) void main_k(
    const unsigned short* __restrict__ wtp, const float* __restrict__ x,
    const float* __restrict__ bias, float* __restrict__ out)
{
    __shared__ unsigned short Xs[25600];   // 51200 B, granule-XOR swizzled
    int bx = blockIdx.x;                   // (n*5+d0)*10 + h0, 800 total
    int h0 = bx % 10;
    int d0 = (bx / 10) % 5;
    int n  = bx / 50;
    int tid = threadIdx.x;

    // ---- stage Xs directly from x (fp32 -> bf16, transpose, swizzle) ----
    int id0 = 3 * d0 - 1, ih0 = 3 * h0 - 1;
#pragma unroll 5
    for (int u = tid; u < 6400; u += 256) {
        int q  = u & 7;            // float4 index: iw = 4q..4q+3
        int ci = (u >> 3) & 31;
        int p  = u >> 8;           // dd*5+hl
        int dd = p / 5, hl = p % 5;
        int id = id0 + dd, ih = ih0 + hl;
        float4 v = {0.f, 0.f, 0.f, 0.f};
        if (id >= 0 && ih >= 0)
            v = ((const float4*)(x + (((size_t)(n * CIN + ci) * D + id) * H + ih) * W))[q];
        unsigned short hj[4];
        {
            __hip_bfloat16 b0 = __float2bfloat16(v.x); hj[0] = *reinterpret_cast<unsigned short*>(&b0);
            __hip_bfloat16 b1 = __float2bfloat16(v.y); hj[1] = *reinterpret_cast<unsigned short*>(&b1);
            __hip_bfloat16 b2 = __float2bfloat16(v.z); hj[2] = *reinterpret_cast<unsigned short*>(&b2);
            __hip_bfloat16 b3 = __float2bfloat16(v.w); hj[3] = *reinterpret_cast<unsigned short*>(&b3);
        }
        int rowb = p * 1024;
        int cig = ci >> 3, cil = ci & 7;
#pragma unroll
        for (int j = 0; j < 4; ++j) {
            int ww = 4 * q + 1 + j;
            if (ww < 32)
                Xs[rowb + ww * 32 + ((cig ^ ((ww >> 1) & 3)) << 3) + cil] = hj[j];
        }
        if (q == 0)
            Xs[rowb + (cig << 3) + cil] = 0;   // ww=0 (iw=-1) zero pad
    }

    int lane = tid & 63, wv = tid >> 6;
    int l15 = lane & 15, quad = lane >> 4;
    int wv_s = __builtin_amdgcn_readfirstlane(wv);

    int laneB = l15 * 64 + quad * 16;
    int m1 = 16 + l15; if (m1 > 29) m1 = 29;
    int lp00 = lpA(l15 + 0, quad), lp01 = lpA(l15 + 1, quad), lp02 = lpA(l15 + 2, quad);
    int lp10 = lpA(m1 + 0, quad),  lp11 = lpA(m1 + 1, quad),  lp12 = lpA(m1 + 2, quad);

    // per-thread window-fold selects (fixed per quad/mt)
    int fsm0 = (0x3123 >> (quad * 4)) & 15;
    int fsm1 = (0x4312 >> (quad * 4)) & 15;

    // running per-window partial maxima: [mt][nt][pA/pB]
    float mxp[2][4][2];
#pragma unroll
    for (int mt = 0; mt < 2; ++mt)
#pragma unroll
        for (int nt = 0; nt < 4; ++nt) { mxp[mt][nt][0] = -INFINITY; mxp[mt][nt][1] = -INFINITY; }

    __syncthreads();
    const char* xsb = (const char*)Xs;

    int it0 = IT_START[wv_s], it1 = IT_START[wv_s + 1];
#pragma unroll 1
    for (int ii = it0; ii < it1; ++ii) {
        int code  = __builtin_amdgcn_readfirstlane(IT_CODE[ii]);
        int cls   = code & 7;
        int alpha = code >> 3;
        int ntd = 3 - ((cls >> 2) & 1), nth = 3 - ((cls >> 1) & 1), ntw = 3 - (cls & 1);
        const char* tbb = (const char*)wtp + (size_t)cls * 27 * 4096 + laneB;
        const int T  = ntd * nth * ntw;        // 8/12/18/27
        const int Tp = ((T + 5) / 6) * 6;      // consumption padded to x6

        f32x4 acc[3][2][4];
#pragma unroll
        for (int b = 0; b < 3; ++b)
#pragma unroll
            for (int mt = 0; mt < 2; ++mt)
#pragma unroll
                for (int nt = 0; nt < 4; ++nt) acc[b][mt][nt] = (f32x4){0.f, 0.f, 0.f, 0.f};

        // independent clamped walkers for A (depth 2) and B (depth 3)
        int aptd = 0, apth = 0, aptw = 0, jA = 0;
        int bptd = 0, bpth = 0, bptw = 0, jB = 0;

        bf16x8 aE0, aE1, aE2, aE3, aE4, aE5;
        bf16x8 aO0, aO1, aO2, aO3, aO4, aO5;
        bf16x8 bA0, bA1, bA2, bA3;
        bf16x8 bB0, bB1, bB2, bB3;
        bf16x8 bC0, bC1, bC2, bC3;

        // prologue: B taps 0,1,2 in flight; A taps 0,1
        LOADB(bA) LOADB(bB) LOADB(bC)
        LOADA(E)  LOADA(O)

        // steady: 6-tap statically-rotated body; B reload 3 bursts before reuse
#pragma unroll 1
        for (int t = 0; t < Tp; t += 6) {
            BURST(E, bA) LOADA(E) LOADB(bA)
            BURST(O, bB) LOADA(O) LOADB(bB)
            BURST(E, bC) LOADA(E) LOADB(bC)
            BURST(O, bA) LOADA(O) LOADB(bA)
            BURST(E, bB) LOADA(E) LOADB(bB)
            BURST(O, bC) LOADA(O) LOADB(bC)
        }

        // fold item: 3 b-planes -> gamma rows -> window partials (ladder commutes with max)
#pragma unroll
        for (int mt = 0; mt < 2; ++mt) {
            int fs = mt ? fsm1 : fsm0;
#pragma unroll
            for (int nt = 0; nt < 4; ++nt) {
                float r0 = fmaxf(fmaxf(acc[0][mt][nt][0], acc[1][mt][nt][0]), acc[2][mt][nt][0]);
                float r1 = fmaxf(fmaxf(acc[0][mt][nt][1], acc[1][mt][nt][1]), acc[2][mt][nt][1]);
                float r2 = fmaxf(fmaxf(acc[0][mt][nt][2], acc[1][mt][nt][2]), acc[2][mt][nt][2]);
                float r3 = fmaxf(fmaxf(acc[0][mt][nt][3], acc[1][mt][nt][3]), acc[2][mt][nt][3]);
                float t01 = fmaxf(r0, r1), t012 = fmaxf(t01, r2), t0123 = fmaxf(t012, r3);
                float pA = fs == 1 ? r0 : (fs == 2 ? t01 : (fs == 3 ? t012 : t0123));
                float t23 = fmaxf(r2, r3), t123 = fmaxf(r1, t23);
                float pB = fs == 1 ? t123 : (fs == 2 ? t23 : (fs == 3 ? r3 : -INFINITY));
                mxp[mt][nt][0] = fmaxf(mxp[mt][nt][0], pA);
                mxp[mt][nt][1] = fmaxf(mxp[mt][nt][1], pB);
            }
        }
    }

    // ---- epilogue: cross-wave max, bias, co-sum ----
    __syncthreads();                 // Xs reads done; reuse as epi buffer
    float* epi = (float*)Xs;
#pragma unroll
    for (int mt = 0; mt < 2; ++mt) {
        int g = mt * 4 + quad;
#pragma unroll
        for (int nt = 0; nt < 4; ++nt) {
            epi[((wv * 8 + g) * 2 + 0) * 64 + nt * 16 + l15] = mxp[mt][nt][0];
            epi[((wv * 8 + g) * 2 + 1) * 64 + nt * 16 + l15] = mxp[mt][nt][1];
        }
    }
    __syncthreads();

    int elemBase = ((n * 5 + d0) * 10 + h0) * 10;
    float bco = bias[lane];
#pragma unroll 1
    for (int win = wv_s; win < 10; win += 4) {
        int st = EPI_START[win], cnt = EPI_CNT[win];
        float v = -INFINITY;
        for (int src = 0; src < 4; ++src)
            for (int e = st; e < st + cnt; ++e)
                v = fmaxf(v, epi[(src * 16 + e) * 64 + lane]);
        v += bco;
#pragma unroll
        for (int off = 32; off > 0; off >>= 1) v += __shfl_xor(v, off);
        if (lane == 0) out[elemBase + win] = v;
    }
}

// ---------------- fallback (round-1 kernel, no ws needed) ----------------
__global__ __launch_bounds__(256) void fused_fallback(
    const float* __restrict__ x, const float* __restrict__ wsrc,
    const float* __restrict__ bias, float* __restrict__ out)
{
    __shared__ float xs[CIN * 125];
    __shared__ float wmax[4][64];
    const int b  = blockIdx.x;
    const int w0 = b % 10, h0 = (b / 10) % 10, d0 = (b / 100) % 5, n = b / 500;
    const int tid = threadIdx.x;
    const int id0 = 3 * d0 - 1, ih0 = 3 * h0 - 1, iw0 = 3 * w0 - 1;
    for (int e = tid; e < CIN * 125; e += 256) {
        int kk = e % 5, jj = (e / 5) % 5, ii = (e / 25) % 5, c = e / 125;
        int id = id0 + ii, ih = ih0 + jj, iw = iw0 + kk;
        float v = 0.f;
        if (id >= 0 && ih >= 0 && iw >= 0)
            v = x[(((n * CIN + c) * D + id) * H + ih) * W + iw];
        xs[e] = v;
    }
    __syncthreads();
    const int lane = tid & 63, wv = tid >> 6;
    float lmax = -INFINITY;
    for (int ccls = 0; ccls < 2; ++ccls) {
        const int cls = wv * 2 + ccls;
        const int pd = (cls >> 2) & 1, ph = (cls >> 1) & 1, pw = cls & 1;
        float acc[27];
#pragma unroll
        for (int i = 0; i < 27; ++i) acc[i] = 0.f;
        for (int ci = 0; ci < CIN; ++ci) {
            float wr[27];
#pragma unroll
            for (int t = 0; t < 27; ++t) {
                int td = t / 9, th = (t / 3) % 3, tw = t % 3;
                int kd = pd + 2 * td, kh = ph + 2 * th, kw = pw + 2 * tw;
                wr[t] = (kd < 5 && kh < 5 && kw < 5)
                          ? wsrc[((ci * 64 + lane) * 125) + kd * 25 + kh * 5 + kw] : 0.f;
            }
            const float* xb = xs + ci * 125;
#pragma unroll
            for (int td = 0; td < 3; ++td)
#pragma unroll
            for (int th = 0; th < 3; ++th)
#pragma unroll
            for (int tw = 0; tw < 3; ++tw) {
                const float wval = wr[(td * 3 + th) * 3 + tw];
#pragma unroll
                for (int a = 0; a < 3; ++a)
#pragma unroll
                for (int bb = 0; bb < 3; ++bb)
#pragma unroll
                for (int cc = 0; cc < 3; ++cc)
                    acc[(a * 3 + bb) * 3 + cc] +=
                        xb[(a + 2 - td) * 25 + (bb + 2 - th) * 5 + (cc + 2 - tw)] * wval;
            }
        }
#pragma unroll
        for (int i = 0; i < 27; ++i) lmax = fmaxf(lmax, acc[i]);
    }
    wmax[wv][lane] = lmax;
    __syncthreads();
    if (wv == 0) {
        float m = fmaxf(fmaxf(wmax[0][lane], wmax[1][lane]),
                        fmaxf(wmax[2][lane], wmax[3][lane]));
        m += bias[lane];
        for (int off = 32; off > 0; off >>= 1) m += __shfl_down(m, off);
        if (lane == 0) out[b] = m;
    }
}

extern "C" void kernel_launch(void* const* d_in, const int* in_sizes, int n_in,
                              void* d_out, int out_size, void* d_ws, size_t ws_size,
                              hipStream_t stream) {
    const float* x    = (const float*)d_in[0];
    const float* w    = (const float*)d_in[1];
    const float* bias = (const float*)d_in[2];
    float* out = (float*)d_out;

    if (ws_size >= WS_NEED) {
        unsigned short* wtp = (unsigned short*)d_ws;
        prep_w<<<1728, 256, 0, stream>>>(w, wtp);
        main_k<<<800, 256, 0, stream>>>(wtp, x, bias, out);
    } else {
        fused_fallback<<<8000, 256, 0, stream>>>(x, w, bias, out);
    }
}

// Round 6
// 212.467 us; speedup vs baseline: 1.0846x; 1.0846x over previous
//
#include <hip/hip_runtime.h>
#include <hip/hip_bf16.h>
#include <math.h>

typedef short bf16x8 __attribute__((ext_vector_type(8)));
typedef float f32x16 __attribute__((ext_vector_type(16)));

constexpr int CIN = 32, COUT = 64, D = 16, H = 32, W = 32;

// ---------------- ws layout ----------------
// [0, 884736) : wtp bf16 [cls8][t27][co64][ci32]
constexpr size_t WS_NEED = 884736u;

// Per-wave item lists (full-co): item = (cls, alpha), code = cls + alpha*8.
static __device__ const unsigned char IT_CODE[24] = {
    0, 8, 16, 3,                  // w0 (93 taps)
    1, 9, 17, 11, 19, 7,          // w1 (86)
    2, 10, 18, 5, 13, 21, 15,     // w2 (98)
    4, 12, 20, 6, 14, 22, 23};    // w3 (98)
static __device__ const unsigned char IT_START[5] = {0, 4, 10, 17, 24};

__global__ void prep_w(const float* __restrict__ w, unsigned short* __restrict__ wtp) {
    int idx = blockIdx.x * 256 + threadIdx.x;            // 442368 total
    int ci  = idx & 31;
    int co  = (idx >> 5) & 63;
    int tt  = idx >> 11;                                  // cls*27 + t
    int t   = tt % 27, cls = tt / 27;
    int td = t / 9, th = (t / 3) % 3, tw = t % 3;
    int pd = (cls >> 2) & 1, ph = (cls >> 1) & 1, pw = cls & 1;
    int kd = pd + 2 * td, kh = ph + 2 * th, kw = pw + 2 * tw;
    float v = 0.f;
    if (kd < 5 && kh < 5 && kw < 5)
        v = w[(ci * COUT + co) * 125 + kd * 25 + kh * 5 + kw];
    __hip_bfloat16 b = __float2bfloat16(v);
    wtp[idx] = *reinterpret_cast<unsigned short*>(&b);
}

__device__ __forceinline__ int lpA32(int row, int g) {
    return row * 64 + ((g ^ ((row >> 1) & 3)) << 4);
}

#define RFL(x) __builtin_amdgcn_readfirstlane(x)

// load A (LDS) + B (global) fragments for the walker's current tap into set S
#define LOADTAP(S)                                                                   \
    {                                                                                \
        int Boff = RFL((ptd * 9 + pth * 3 + ptw) * 4096);                            \
        int Qb   = RFL(((alpha + 2 - ptd) * 5 + (2 - pth)) * 2048);                  \
        int ss   = RFL(2 - ptw);                                                     \
        const char* bq = tbb + Boff;                                                 \
        b##S##00 = *(const bf16x8*)(bq);                                             \
        b##S##01 = *(const bf16x8*)(bq + 32);                                        \
        b##S##10 = *(const bf16x8*)(bq + 2048);                                      \
        b##S##11 = *(const bf16x8*)(bq + 2048 + 32);                                 \
        int la0 = ss == 0 ? lpx00 : (ss == 1 ? lpx10 : lpx20);                       \
        int la1 = ss == 0 ? lpx01 : (ss == 1 ? lpx11 : lpx21);                       \
        const char* rb = xsb + Qb;                                                   \
        a##S##00 = *(const bf16x8*)(rb + la0);                                       \
        a##S##01 = *(const bf16x8*)(rb + la1);                                       \
        a##S##10 = *(const bf16x8*)(rb + 2048 + la0);                                \
        a##S##11 = *(const bf16x8*)(rb + 2048 + la1);                                \
        a##S##20 = *(const bf16x8*)(rb + 4096 + la0);                                \
        a##S##21 = *(const bf16x8*)(rb + 4096 + la1);                                \
    }

// 12 x mfma_32x32x16 per tap: kh0 sextet then kh1 sextet (acc RAW gap = 6 ops)
#define BURST(S)                                                                     \
    __builtin_amdgcn_s_setprio(1);                                                   \
    c00 = __builtin_amdgcn_mfma_f32_32x32x16_bf16(a##S##00, b##S##00, c00, 0, 0, 0); \
    c01 = __builtin_amdgcn_mfma_f32_32x32x16_bf16(a##S##00, b##S##10, c01, 0, 0, 0); \
    c10 = __builtin_amdgcn_mfma_f32_32x32x16_bf16(a##S##10, b##S##00, c10, 0, 0, 0); \
    c11 = __builtin_amdgcn_mfma_f32_32x32x16_bf16(a##S##10, b##S##10, c11, 0, 0, 0); \
    c20 = __builtin_amdgcn_mfma_f32_32x32x16_bf16(a##S##20, b##S##00, c20, 0, 0, 0); \
    c21 = __builtin_amdgcn_mfma_f32_32x32x16_bf16(a##S##20, b##S##10, c21, 0, 0, 0); \
    c00 = __builtin_amdgcn_mfma_f32_32x32x16_bf16(a##S##01, b##S##01, c00, 0, 0, 0); \
    c01 = __builtin_amdgcn_mfma_f32_32x32x16_bf16(a##S##01, b##S##11, c01, 0, 0, 0); \
    c10 = __builtin_amdgcn_mfma_f32_32x32x16_bf16(a##S##11, b##S##01, c10, 0, 0, 0); \
    c11 = __builtin_amdgcn_mfma_f32_32x32x16_bf16(a##S##11, b##S##11, c11, 0, 0, 0); \
    c20 = __builtin_amdgcn_mfma_f32_32x32x16_bf16(a##S##21, b##S##01, c20, 0, 0, 0); \
    c21 = __builtin_amdgcn_mfma_f32_32x32x16_bf16(a##S##21, b##S##11, c21, 0, 0, 0); \
    __builtin_amdgcn_s_setprio(0);

// fold one nt-tile: 3 beta-planes -> rows -> per-half window slots -> mxp
#define FOLDNT(NT, A0, A1, A2)                                                       \
    {                                                                                \
        float r[16];                                                                 \
        _Pragma("unroll")                                                            \
        for (int i = 0; i < 16; ++i) r[i] = fmaxf(fmaxf(A0[i], A1[i]), A2[i]);       \
        float s0 = half ? fmaxf(r[0], r[1]) : fmaxf(fmaxf(r[0], r[1]), r[2]);        \
        float s1 = half ? fmaxf(r[2], r[3]) : r[3];                                  \
        float s2 = half ? fmaxf(fmaxf(r[4], r[5]), r[6]) : r[4];                     \
        float s3 = half ? r[7] : fmaxf(fmaxf(r[5], r[6]), r[7]);                     \
        float s4 = half ? r[8] : fmaxf(r[8], r[9]);                                  \
        float s5 = half ? fmaxf(fmaxf(r[9], r[10]), r[11]) : fmaxf(r[10], r[11]);    \
        float s6 = half ? fmaxf(r[12], r[13]) : fmaxf(fmaxf(r[12], r[13]), r[14]);   \
        float s7 = half ? -INFINITY : r[15];                                         \
        mxp[NT][0] = fmaxf(mxp[NT][0], s0);                                          \
        mxp[NT][1] = fmaxf(mxp[NT][1], s1);                                          \
        mxp[NT][2] = fmaxf(mxp[NT][2], s2);                                          \
        mxp[NT][3] = fmaxf(mxp[NT][3], s3);                                          \
        mxp[NT][4] = fmaxf(mxp[NT][4], s4);                                          \
        mxp[NT][5] = fmaxf(mxp[NT][5], s5);                                          \
        mxp[NT][6] = fmaxf(mxp[NT][6], s6);                                          \
        mxp[NT][7] = fmaxf(mxp[NT][7], s7);                                          \
    }

__global__ __launch_bounds__(256, 2) void main_k(
    const unsigned short* __restrict__ wtp, const float* __restrict__ x,
    const float* __restrict__ bias, float* __restrict__ out)
{
    __shared__ unsigned short Xs[25600];   // 51200 B, granule-XOR swizzled
    int bx = blockIdx.x;                   // (n*5+d0)*10 + h0, 800 total
    int h0 = bx % 10;
    int d0 = (bx / 10) % 5;
    int n  = bx / 50;
    int tid = threadIdx.x;

    // ---- stage Xs directly from x (fp32 -> bf16, transpose, swizzle) ----
    int id0 = 3 * d0 - 1, ih0 = 3 * h0 - 1;
#pragma unroll 5
    for (int u = tid; u < 6400; u += 256) {
        int q  = u & 7;            // float4 index: iw = 4q..4q+3
        int ci = (u >> 3) & 31;
        int p  = u >> 8;           // dd*5+hl
        int dd = p / 5, hl = p % 5;
        int id = id0 + dd, ih = ih0 + hl;
        float4 v = {0.f, 0.f, 0.f, 0.f};
        if (id >= 0 && ih >= 0)
            v = ((const float4*)(x + (((size_t)(n * CIN + ci) * D + id) * H + ih) * W))[q];
        unsigned short hj[4];
        {
            __hip_bfloat16 b0 = __float2bfloat16(v.x); hj[0] = *reinterpret_cast<unsigned short*>(&b0);
            __hip_bfloat16 b1 = __float2bfloat16(v.y); hj[1] = *reinterpret_cast<unsigned short*>(&b1);
            __hip_bfloat16 b2 = __float2bfloat16(v.z); hj[2] = *reinterpret_cast<unsigned short*>(&b2);
            __hip_bfloat16 b3 = __float2bfloat16(v.w); hj[3] = *reinterpret_cast<unsigned short*>(&b3);
        }
        int rowb = p * 1024;
        int cig = ci >> 3, cil = ci & 7;
#pragma unroll
        for (int j = 0; j < 4; ++j) {
            int ww = 4 * q + 1 + j;
            if (ww < 32)
                Xs[rowb + ww * 32 + ((cig ^ ((ww >> 1) & 3)) << 3) + cil] = hj[j];
        }
        if (q == 0)
            Xs[rowb + (cig << 3) + cil] = 0;   // ww=0 (iw=-1) zero pad
    }

    int lane = tid & 63, wv = tid >> 6;
    int l31 = lane & 31, half = lane >> 5;
    int wv_s = __builtin_amdgcn_readfirstlane(wv);

    // B fragment base: col(co) = l31, k-granule = half
    int laneB32 = l31 * 64 + (half << 4);

    // A fragment offsets lpx[ss][kh]: row = min(l31+ss, 31), granule g = half + 2*kh
    int r0c = l31, r1c = l31 + 1 > 31 ? 31 : l31 + 1, r2c = l31 + 2 > 31 ? 31 : l31 + 2;
    int lpx00 = lpA32(r0c, half),     lpx01 = lpA32(r0c, half + 2);
    int lpx10 = lpA32(r1c, half),     lpx11 = lpA32(r1c, half + 2);
    int lpx20 = lpA32(r2c, half),     lpx21 = lpA32(r2c, half + 2);

    float mxp[2][8];
#pragma unroll
    for (int nt = 0; nt < 2; ++nt)
#pragma unroll
        for (int s = 0; s < 8; ++s) mxp[nt][s] = -INFINITY;

    __syncthreads();
    const char* xsb = (const char*)Xs;

    int it0 = IT_START[wv_s], it1 = IT_START[wv_s + 1];
#pragma unroll 1
    for (int ii = it0; ii < it1; ++ii) {
        int code  = RFL(IT_CODE[ii]);
        int cls   = code & 7;
        int alpha = code >> 3;
        int ntd = 3 - ((cls >> 2) & 1), nth = 3 - ((cls >> 1) & 1), ntw = 3 - (cls & 1);
        const char* tbb = (const char*)wtp + (size_t)cls * 27 * 4096 + laneB32;
        const int T = ntd * nth * ntw;   // 8/12/18/27

        f32x16 c00 = {}, c01 = {}, c10 = {}, c11 = {}, c20 = {}, c21 = {};

        int ptd = 0, pth = 0, ptw = 0;   // state = next unissued tap
        auto adv = [&]() {
            ++ptw;
            if (ptw == ntw) { ptw = 0; ++pth; if (pth == nth) { pth = 0; ++ptd; } }
        };

        bf16x8 aE00, aE01, aE10, aE11, aE20, aE21, bE00, bE01, bE10, bE11;
        bf16x8 aO00, aO01, aO10, aO11, aO20, aO21, bO00, bO01, bO10, bO11;
        LOADTAP(E) adv();
        LOADTAP(O) adv();

#pragma unroll 1
        for (int t = 0; t < T; t += 2) {
            BURST(E)
            if (t + 2 < T) { LOADTAP(E) adv(); }
            if (t + 1 < T) {
                BURST(O)
                if (t + 3 < T) { LOADTAP(O) adv(); }
            }
        }

        FOLDNT(0, c00, c10, c20)
        FOLDNT(1, c01, c11, c21)
    }

    // ---- epilogue: LDS [win10][src8][co64] max-reduce, bias, co-sum ----
    __syncthreads();                 // Xs reads done; reuse as epi buffer
    float* epi = (float*)Xs;         // 5120 floats = 20 KiB
    for (int u = tid; u < 5120; u += 256) epi[u] = -INFINITY;
    __syncthreads();
    {
        int src = wv * 2 + half;     // 0..7
        const int w0tab[8] = {0, 1, 2, 3, 5, 6, 8, 9};
        const int w1tab[8] = {1, 2, 4, 5, 6, 7, 9, 9};
#pragma unroll
        for (int s = 0; s < 8; ++s) {
            int wn = half ? w1tab[s] : w0tab[s];
            if (!half || s < 7) {
                epi[(wn * 8 + src) * 64 + l31]      = mxp[0][s];
                epi[(wn * 8 + src) * 64 + 32 + l31] = mxp[1][s];
            }
        }
    }
    __syncthreads();

    int elemBase = ((n * 5 + d0) * 10 + h0) * 10;
    float bco = bias[lane];
#pragma unroll 1
    for (int win = wv_s; win < 10; win += 4) {
        float v = -INFINITY;
#pragma unroll
        for (int s = 0; s < 8; ++s) v = fmaxf(v, epi[(win * 8 + s) * 64 + lane]);
        v += bco;
#pragma unroll
        for (int off = 32; off > 0; off >>= 1) v += __shfl_xor(v, off);
        if (lane == 0) out[elemBase + win] = v;
    }
}

// ---------------- fallback (round-1 kernel, no ws needed) ----------------
__global__ __launch_bounds__(256) void fused_fallback(
    const float* __restrict__ x, const float* __restrict__ wsrc,
    const float* __restrict__ bias, float* __restrict__ out)
{
    __shared__ float xs[CIN * 125];
    __shared__ float wmax[4][64];
    const int b  = blockIdx.x;
    const int w0 = b % 10, h0 = (b / 10) % 10, d0 = (b / 100) % 5, n = b / 500;
    const int tid = threadIdx.x;
    const int id0 = 3 * d0 - 1, ih0 = 3 * h0 - 1, iw0 = 3 * w0 - 1;
    for (int e = tid; e < CIN * 125; e += 256) {
        int kk = e % 5, jj = (e / 5) % 5, ii = (e / 25) % 5, c = e / 125;
        int id = id0 + ii, ih = ih0 + jj, iw = iw0 + kk;
        float v = 0.f;
        if (id >= 0 && ih >= 0 && iw >= 0)
            v = x[(((n * CIN + c) * D + id) * H + ih) * W + iw];
        xs[e] = v;
    }
    __syncthreads();
    const int lane = tid & 63, wv = tid >> 6;
    float lmax = -INFINITY;
    for (int ccls = 0; ccls < 2; ++ccls) {
        const int cls = wv * 2 + ccls;
        const int pd = (cls >> 2) & 1, ph = (cls >> 1) & 1, pw = cls & 1;
        float acc[27];
#pragma unroll
        for (int i = 0; i < 27; ++i) acc[i] = 0.f;
        for (int ci = 0; ci < CIN; ++ci) {
            float wr[27];
#pragma unroll
            for (int t = 0; t < 27; ++t) {
                int td = t / 9, th = (t / 3) % 3, tw = t % 3;
                int kd = pd + 2 * td, kh = ph + 2 * th, kw = pw + 2 * tw;
                wr[t] = (kd < 5 && kh < 5 && kw < 5)
                          ? wsrc[((ci * 64 + lane) * 125) + kd * 25 + kh * 5 + kw] : 0.f;
            }
            const float* xb = xs + ci * 125;
#pragma unroll
            for (int td = 0; td < 3; ++td)
#pragma unroll
            for (int th = 0; th < 3; ++th)
#pragma unroll
            for (int tw = 0; tw < 3; ++tw) {
                const float wval = wr[(td * 3 + th) * 3 + tw];
#pragma unroll
                for (int a = 0; a < 3; ++a)
#pragma unroll
                for (int bb = 0; bb < 3; ++bb)
#pragma unroll
                for (int cc = 0; cc < 3; ++cc)
                    acc[(a * 3 + bb) * 3 + cc] +=
                        xb[(a + 2 - td) * 25 + (bb + 2 - th) * 5 + (cc + 2 - tw)] * wval;
            }
        }
#pragma unroll
        for (int i = 0; i < 27; ++i) lmax = fmaxf(lmax, acc[i]);
    }
    wmax[wv][lane] = lmax;
    __syncthreads();
    if (wv == 0) {
        float m = fmaxf(fmaxf(wmax[0][lane], wmax[1][lane]),
                        fmaxf(wmax[2][lane], wmax[3][lane]));
        m += bias[lane];
        for (int off = 32; off > 0; off >>= 1) m += __shfl_down(m, off);
        if (lane == 0) out[b] = m;
    }
}

extern "C" void kernel_launch(void* const* d_in, const int* in_sizes, int n_in,
                              void* d_out, int out_size, void* d_ws, size_t ws_size,
                              hipStream_t stream) {
    const float* x    = (const float*)d_in[0];
    const float* w    = (const float*)d_in[1];
    const float* bias = (const float*)d_in[2];
    float* out = (float*)d_out;

    if (ws_size >= WS_NEED) {
        unsigned short* wtp = (unsigned short*)d_ws;
        prep_w<<<1728, 256, 0, stream>>>(w, wtp);
        main_k<<<800, 256, 0, stream>>>(wtp, x, bias, out);
    } else {
        fused_fallback<<<8000, 256, 0, stream>>>(x, w, bias, out);
    }
}

// Round 7
// 197.379 us; speedup vs baseline: 1.1675x; 1.0764x over previous
//
#include <hip/hip_runtime.h>
#include <hip/hip_bf16.h>
#include <math.h>

typedef short bf16x8 __attribute__((ext_vector_type(8)));
typedef float f32x4 __attribute__((ext_vector_type(4)));

constexpr int CIN = 32, COUT = 64, D = 16, H = 32, W = 32;

// ---------------- ws layout ----------------
// [0, 884736) : wtp bf16 [cls8][t27][co64][ci32]
constexpr size_t WS_NEED = 884736u;

// Per-wave-pair item lists: item = (cls, alpha), code = cls + alpha*8.
static __device__ const unsigned char IT_CODE[24] = {
    0, 8, 16, 3,                  // list0 (93 taps)
    1, 9, 17, 11, 19, 7,          // list1 (86)
    2, 10, 18, 5, 13, 21, 15,     // list2 (98)
    4, 12, 20, 6, 14, 22, 23};    // list3 (98)
static __device__ const unsigned char IT_START[5] = {0, 4, 10, 17, 24};
static __device__ const unsigned char EPI_START[10] = {0, 1, 3, 5, 6, 7, 9, 11, 12, 13};
static __device__ const unsigned char EPI_CNT[10]   = {1, 2, 2, 1, 1, 2, 2, 1, 1, 2};

__global__ void prep_w(const float* __restrict__ w, unsigned short* __restrict__ wtp) {
    int idx = blockIdx.x * 256 + threadIdx.x;            // 442368 total
    int ci  = idx & 31;
    int co  = (idx >> 5) & 63;
    int tt  = idx >> 11;                                  // cls*27 + t
    int t   = tt % 27, cls = tt / 27;
    int td = t / 9, th = (t / 3) % 3, tw = t % 3;
    int pd = (cls >> 2) & 1, ph = (cls >> 1) & 1, pw = cls & 1;
    int kd = pd + 2 * td, kh = ph + 2 * th, kw = pw + 2 * tw;
    float v = 0.f;
    if (kd < 5 && kh < 5 && kw < 5)
        v = w[(ci * COUT + co) * 125 + kd * 25 + kh * 5 + kw];
    __hip_bfloat16 b = __float2bfloat16(v);
    wtp[idx] = *reinterpret_cast<unsigned short*>(&b);
}

__device__ __forceinline__ int lpA(int wrow, int quad) {
    return wrow * 64 + ((quad ^ ((wrow >> 1) & 3)) << 4);
}

#define RFL(x) __builtin_amdgcn_readfirstlane(x)

// 12 MFMA per tap: single A set (aa0..aa5), B pair of one E/O set
#define BURST(bp)                                                                          \
    __builtin_amdgcn_s_setprio(1);                                                         \
    acc[0][0][0] = __builtin_amdgcn_mfma_f32_16x16x32_bf16(aa0, bp##0, acc[0][0][0], 0, 0, 0); \
    acc[0][1][0] = __builtin_amdgcn_mfma_f32_16x16x32_bf16(aa1, bp##0, acc[0][1][0], 0, 0, 0); \
    acc[1][0][0] = __builtin_amdgcn_mfma_f32_16x16x32_bf16(aa2, bp##0, acc[1][0][0], 0, 0, 0); \
    acc[1][1][0] = __builtin_amdgcn_mfma_f32_16x16x32_bf16(aa3, bp##0, acc[1][1][0], 0, 0, 0); \
    acc[2][0][0] = __builtin_amdgcn_mfma_f32_16x16x32_bf16(aa4, bp##0, acc[2][0][0], 0, 0, 0); \
    acc[2][1][0] = __builtin_amdgcn_mfma_f32_16x16x32_bf16(aa5, bp##0, acc[2][1][0], 0, 0, 0); \
    acc[0][0][1] = __builtin_amdgcn_mfma_f32_16x16x32_bf16(aa0, bp##1, acc[0][0][1], 0, 0, 0); \
    acc[0][1][1] = __builtin_amdgcn_mfma_f32_16x16x32_bf16(aa1, bp##1, acc[0][1][1], 0, 0, 0); \
    acc[1][0][1] = __builtin_amdgcn_mfma_f32_16x16x32_bf16(aa2, bp##1, acc[1][0][1], 0, 0, 0); \
    acc[1][1][1] = __builtin_amdgcn_mfma_f32_16x16x32_bf16(aa3, bp##1, acc[1][1][1], 0, 0, 0); \
    acc[2][0][1] = __builtin_amdgcn_mfma_f32_16x16x32_bf16(aa4, bp##1, acc[2][0][1], 0, 0, 0); \
    acc[2][1][1] = __builtin_amdgcn_mfma_f32_16x16x32_bf16(aa5, bp##1, acc[2][1][1], 0, 0, 0); \
    __builtin_amdgcn_s_setprio(0);

// A load (LDS) from A-walker state (leads consumption by 1 tap)
#define LOADA()                                                                      \
    {                                                                                \
        int Qb = RFL(((alpha + 2 - aptd) * 5 + (2 - apth)) * 2048);                  \
        int ss = RFL(2 - aptw);                                                      \
        int la = ss == 0 ? lp00 : (ss == 1 ? lp01 : lp02);                           \
        int lb = ss == 0 ? lp10 : (ss == 1 ? lp11 : lp12);                           \
        const char* rb = xsb + Qb;                                                   \
        aa0 = *(const bf16x8*)(rb + la);                                             \
        aa1 = *(const bf16x8*)(rb + lb);                                             \
        aa2 = *(const bf16x8*)(rb + 2048 + la);                                      \
        aa3 = *(const bf16x8*)(rb + 2048 + lb);                                      \
        aa4 = *(const bf16x8*)(rb + 4096 + la);                                      \
        aa5 = *(const bf16x8*)(rb + 4096 + lb);                                      \
    }
#define ADVA()                                                                       \
    { ++aptw; if (aptw == ntw) { aptw = 0; ++apth; if (apth == nth) { apth = 0; ++aptd; } } }

// B load (global, co-half = 2 frags) from B-walker state (leads by 2 taps)
#define LOADB(S)                                                                     \
    {                                                                                \
        int Boff = RFL((bptd * 9 + bpth * 3 + bptw) * 4096);                         \
        b##S##0 = *(const bf16x8*)(tbb + Boff);                                      \
        b##S##1 = *(const bf16x8*)(tbb + Boff + 1024);                               \
    }
#define ADVB()                                                                       \
    { ++bptw; if (bptw == ntw) { bptw = 0; ++bpth; if (bpth == nth) { bpth = 0; ++bptd; } } }

__global__ __launch_bounds__(512, 4) void main_k(
    const unsigned short* __restrict__ wtp, const float* __restrict__ x,
    const float* __restrict__ bias, float* __restrict__ out)
{
    __shared__ unsigned short Xs[25600];   // 51200 B, granule-XOR swizzled
    int bx = blockIdx.x;                   // (n*5+d0)*10 + h0, 800 total
    int h0 = bx % 10;
    int d0 = (bx / 10) % 5;
    int n  = bx / 50;
    int tid = threadIdx.x;

    // ---- stage Xs directly from x (fp32 -> bf16, transpose, swizzle) ----
    int id0 = 3 * d0 - 1, ih0 = 3 * h0 - 1;
#pragma unroll 4
    for (int u = tid; u < 6400; u += 512) {
        int q  = u & 7;            // float4 index: iw = 4q..4q+3
        int ci = (u >> 3) & 31;
        int p  = u >> 8;           // dd*5+hl
        int dd = p / 5, hl = p % 5;
        int id = id0 + dd, ih = ih0 + hl;
        float4 v = {0.f, 0.f, 0.f, 0.f};
        if (id >= 0 && ih >= 0)
            v = ((const float4*)(x + (((size_t)(n * CIN + ci) * D + id) * H + ih) * W))[q];
        unsigned short hj[4];
        {
            __hip_bfloat16 b0 = __float2bfloat16(v.x); hj[0] = *reinterpret_cast<unsigned short*>(&b0);
            __hip_bfloat16 b1 = __float2bfloat16(v.y); hj[1] = *reinterpret_cast<unsigned short*>(&b1);
            __hip_bfloat16 b2 = __float2bfloat16(v.z); hj[2] = *reinterpret_cast<unsigned short*>(&b2);
            __hip_bfloat16 b3 = __float2bfloat16(v.w); hj[3] = *reinterpret_cast<unsigned short*>(&b3);
        }
        int rowb = p * 1024;
        int cig = ci >> 3, cil = ci & 7;
#pragma unroll
        for (int j = 0; j < 4; ++j) {
            int ww = 4 * q + 1 + j;
            if (ww < 32)
                Xs[rowb + ww * 32 + ((cig ^ ((ww >> 1) & 3)) << 3) + cil] = hj[j];
        }
        if (q == 0)
            Xs[rowb + (cig << 3) + cil] = 0;   // ww=0 (iw=-1) zero pad
    }

    int lane = tid & 63, wv = tid >> 6;            // wv 0..7
    int l15 = lane & 15, quad = lane >> 4;
    int wl  = RFL(wv >> 1);                        // item list 0..3
    int coh = RFL(wv & 1);                         // co half 0/1

    int laneB = l15 * 64 + quad * 16;
    int m1 = 16 + l15; if (m1 > 29) m1 = 29;
    int lp00 = lpA(l15 + 0, quad), lp01 = lpA(l15 + 1, quad), lp02 = lpA(l15 + 2, quad);
    int lp10 = lpA(m1 + 0, quad),  lp11 = lpA(m1 + 1, quad),  lp12 = lpA(m1 + 2, quad);

    // per-thread window-fold selects (fixed per quad/mt)
    int fsm0 = (0x3123 >> (quad * 4)) & 15;
    int fsm1 = (0x4312 >> (quad * 4)) & 15;

    // running per-window partial maxima: [mt][nt][pA/pB]
    float mxp[2][2][2];
#pragma unroll
    for (int mt = 0; mt < 2; ++mt)
#pragma unroll
        for (int nt = 0; nt < 2; ++nt) { mxp[mt][nt][0] = -INFINITY; mxp[mt][nt][1] = -INFINITY; }

    __syncthreads();
    const char* xsb = (const char*)Xs;

    int it0 = IT_START[wl], it1 = IT_START[wl + 1];
#pragma unroll 1
    for (int ii = it0; ii < it1; ++ii) {
        int code  = RFL(IT_CODE[ii]);
        int cls   = code & 7;
        int alpha = code >> 3;
        int ntd = 3 - ((cls >> 2) & 1), nth = 3 - ((cls >> 1) & 1), ntw = 3 - (cls & 1);
        const char* tbb = (const char*)wtp + (size_t)cls * 27 * 4096 + coh * 2048 + laneB;
        const int T = ntd * nth * ntw;   // 8/12/18/27

        f32x4 acc[3][2][2];
#pragma unroll
        for (int b = 0; b < 3; ++b)
#pragma unroll
            for (int mt = 0; mt < 2; ++mt)
#pragma unroll
                for (int nt = 0; nt < 2; ++nt) acc[b][mt][nt] = (f32x4){0.f, 0.f, 0.f, 0.f};

        // A-walker (leads consumption by 1), B-walker (leads by 2)
        int aptd = 0, apth = 0, aptw = 0;
        int bptd = 0, bpth = 0, bptw = 0;

        bf16x8 aa0, aa1, aa2, aa3, aa4, aa5;
        bf16x8 bE0, bE1, bO0, bO1;

        LOADB(E) ADVB()          // tap 0
        LOADB(O) ADVB()          // tap 1
        LOADA()                  // tap 0 (A-walker stays at tap 0 until consumed)

#pragma unroll 1
        for (int t = 0; t < T; t += 2) {
            BURST(bE)                                 // tap t (A=aa, B=bE)
            if (t + 1 < T) { ADVA() LOADA() }         // A -> tap t+1
            if (t + 2 < T) { LOADB(E) ADVB() }        // B -> tap t+2
            if (t + 1 < T) {
                BURST(bO)                             // tap t+1
                if (t + 2 < T) { ADVA() LOADA() }     // A -> tap t+2
                if (t + 3 < T) { LOADB(O) ADVB() }    // B -> tap t+3
            }
        }

        // fold item: 3 b-planes -> gamma rows -> window partials
#pragma unroll
        for (int mt = 0; mt < 2; ++mt) {
            int fs = mt ? fsm1 : fsm0;
#pragma unroll
            for (int nt = 0; nt < 2; ++nt) {
                float r0 = fmaxf(fmaxf(acc[0][mt][nt][0], acc[1][mt][nt][0]), acc[2][mt][nt][0]);
                float r1 = fmaxf(fmaxf(acc[0][mt][nt][1], acc[1][mt][nt][1]), acc[2][mt][nt][1]);
                float r2 = fmaxf(fmaxf(acc[0][mt][nt][2], acc[1][mt][nt][2]), acc[2][mt][nt][2]);
                float r3 = fmaxf(fmaxf(acc[0][mt][nt][3], acc[1][mt][nt][3]), acc[2][mt][nt][3]);
                float t01 = fmaxf(r0, r1), t012 = fmaxf(t01, r2), t0123 = fmaxf(t012, r3);
                float pA = fs == 1 ? r0 : (fs == 2 ? t01 : (fs == 3 ? t012 : t0123));
                float t23 = fmaxf(r2, r3), t123 = fmaxf(r1, t23);
                float pB = fs == 1 ? t123 : (fs == 2 ? t23 : (fs == 3 ? r3 : -INFINITY));
                mxp[mt][nt][0] = fmaxf(mxp[mt][nt][0], pA);
                mxp[mt][nt][1] = fmaxf(mxp[mt][nt][1], pB);
            }
        }
    }

    // ---- epilogue: cross-wave max, bias, co-sum ----
    __syncthreads();                 // Xs reads done; reuse as epi buffer
    float* epi = (float*)Xs;         // 64 rows x 64 co = 16 KiB
#pragma unroll
    for (int mt = 0; mt < 2; ++mt) {
        int g = mt * 4 + quad;
#pragma unroll
        for (int nt = 0; nt < 2; ++nt) {
            int co = coh * 32 + nt * 16 + l15;
            epi[((wl * 8 + g) * 2 + 0) * 64 + co] = mxp[mt][nt][0];
            epi[((wl * 8 + g) * 2 + 1) * 64 + co] = mxp[mt][nt][1];
        }
    }
    __syncthreads();

    int elemBase = ((n * 5 + d0) * 10 + h0) * 10;
    float bco = bias[lane];
    int wv_s = RFL(wv);
#pragma unroll 1
    for (int win = wv_s; win < 10; win += 8) {
        int st = EPI_START[win], cnt = EPI_CNT[win];
        float v = -INFINITY;
        for (int src = 0; src < 4; ++src)
            for (int e = st; e < st + cnt; ++e)
                v = fmaxf(v, epi[(src * 16 + e) * 64 + lane]);
        v += bco;
#pragma unroll
        for (int off = 32; off > 0; off >>= 1) v += __shfl_xor(v, off);
        if (lane == 0) out[elemBase + win] = v;
    }
}

// ---------------- fallback (round-1 kernel, no ws needed) ----------------
__global__ __launch_bounds__(256) void fused_fallback(
    const float* __restrict__ x, const float* __restrict__ wsrc,
    const float* __restrict__ bias, float* __restrict__ out)
{
    __shared__ float xs[CIN * 125];
    __shared__ float wmax[4][64];
    const int b  = blockIdx.x;
    const int w0 = b % 10, h0 = (b / 10) % 10, d0 = (b / 100) % 5, n = b / 500;
    const int tid = threadIdx.x;
    const int id0 = 3 * d0 - 1, ih0 = 3 * h0 - 1, iw0 = 3 * w0 - 1;
    for (int e = tid; e < CIN * 125; e += 256) {
        int kk = e % 5, jj = (e / 5) % 5, ii = (e / 25) % 5, c = e / 125;
        int id = id0 + ii, ih = ih0 + jj, iw = iw0 + kk;
        float v = 0.f;
        if (id >= 0 && ih >= 0 && iw >= 0)
            v = x[(((n * CIN + c) * D + id) * H + ih) * W + iw];
        xs[e] = v;
    }
    __syncthreads();
    const int lane = tid & 63, wv = tid >> 6;
    float lmax = -INFINITY;
    for (int ccls = 0; ccls < 2; ++ccls) {
        const int cls = wv * 2 + ccls;
        const int pd = (cls >> 2) & 1, ph = (cls >> 1) & 1, pw = cls & 1;
        float acc[27];
#pragma unroll
        for (int i = 0; i < 27; ++i) acc[i] = 0.f;
        for (int ci = 0; ci < CIN; ++ci) {
            float wr[27];
#pragma unroll
            for (int t = 0; t < 27; ++t) {
                int td = t / 9, th = (t / 3) % 3, tw = t % 3;
                int kd = pd + 2 * td, kh = ph + 2 * th, kw = pw + 2 * tw;
                wr[t] = (kd < 5 && kh < 5 && kw < 5)
                          ? wsrc[((ci * 64 + lane) * 125) + kd * 25 + kh * 5 + kw] : 0.f;
            }
            const float* xb = xs + ci * 125;
#pragma unroll
            for (int td = 0; td < 3; ++td)
#pragma unroll
            for (int th = 0; th < 3; ++th)
#pragma unroll
            for (int tw = 0; tw < 3; ++tw) {
                const float wval = wr[(td * 3 + th) * 3 + tw];
#pragma unroll
                for (int a = 0; a < 3; ++a)
#pragma unroll
                for (int bb = 0; bb < 3; ++bb)
#pragma unroll
                for (int cc = 0; cc < 3; ++cc)
                    acc[(a * 3 + bb) * 3 + cc] +=
                        xb[(a + 2 - td) * 25 + (bb + 2 - th) * 5 + (cc + 2 - tw)] * wval;
            }
        }
#pragma unroll
        for (int i = 0; i < 27; ++i) lmax = fmaxf(lmax, acc[i]);
    }
    wmax[wv][lane] = lmax;
    __syncthreads();
    if (wv == 0) {
        float m = fmaxf(fmaxf(wmax[0][lane], wmax[1][lane]),
                        fmaxf(wmax[2][lane], wmax[3][lane]));
        m += bias[lane];
        for (int off = 32; off > 0; off >>= 1) m += __shfl_down(m, off);
        if (lane == 0) out[b] = m;
    }
}

extern "C" void kernel_launch(void* const* d_in, const int* in_sizes, int n_in,
                              void* d_out, int out_size, void* d_ws, size_t ws_size,
                              hipStream_t stream) {
    const float* x    = (const float*)d_in[0];
    const float* w    = (const float*)d_in[1];
    const float* bias = (const float*)d_in[2];
    float* out = (float*)d_out;

    if (ws_size >= WS_NEED) {
        unsigned short* wtp = (unsigned short*)d_ws;
        prep_w<<<1728, 256, 0, stream>>>(w, wtp);
        main_k<<<800, 512, 0, stream>>>(wtp, x, bias, out);
    } else {
        fused_fallback<<<8000, 256, 0, stream>>>(x, w, bias, out);
    }
}